// Round 5
// baseline (5449.350 us; speedup 1.0000x reference)
//
#include <hip/hip_runtime.h>
#include <math.h>

#define DM 3136
#define DH 512
#define GRID 512
#define NTHR 256

// ---------------- device-wide barrier (generation counter, agent scope) ----------------
__device__ __forceinline__ void gbar(unsigned* bar) {
  __syncthreads();
  if (threadIdx.x == 0) {
    __threadfence();   // release: write back dirty lines (agent scope)
    unsigned g = __hip_atomic_load(&bar[1], __ATOMIC_RELAXED, __HIP_MEMORY_SCOPE_AGENT);
    unsigned old = __hip_atomic_fetch_add(&bar[0], 1u, __ATOMIC_ACQ_REL, __HIP_MEMORY_SCOPE_AGENT);
    if (old == GRID - 1u) {
      __hip_atomic_store(&bar[0], 0u, __ATOMIC_RELAXED, __HIP_MEMORY_SCOPE_AGENT);
      __hip_atomic_fetch_add(&bar[1], 1u, __ATOMIC_RELEASE, __HIP_MEMORY_SCOPE_AGENT);
    } else {
      while (__hip_atomic_load(&bar[1], __ATOMIC_ACQUIRE, __HIP_MEMORY_SCOPE_AGENT) == g)
        __builtin_amdgcn_s_sleep(4);
    }
    __threadfence();   // acquire: invalidate stale lines
  }
  __syncthreads();
}

#define MICRO_4x4 \
    acc[0][0] += a.x*b.x; acc[0][1] += a.x*b.y; acc[0][2] += a.x*b.z; acc[0][3] += a.x*b.w; \
    acc[1][0] += a.y*b.x; acc[1][1] += a.y*b.y; acc[1][2] += a.y*b.z; acc[1][3] += a.y*b.w; \
    acc[2][0] += a.z*b.x; acc[2][1] += a.z*b.y; acc[2][2] += a.z*b.z; acc[2][3] += a.z*b.w; \
    acc[3][0] += a.w*b.x; acc[3][1] += a.w*b.y; acc[3][2] += a.w*b.z; acc[3][3] += a.w*b.w;

// ---------------- gelu ----------------
__device__ __forceinline__ void gelu_both(float xx, float& g, float& gp) {
  const float c = 0.7978845608028654f;
  const float a = 0.044715f;
  float x2 = xx * xx;
  float u = c * (xx + a * xx * x2);
  float t = tanhf(u);
  g  = 0.5f * xx * (1.f + t);
  gp = 0.5f * (1.f + t) + 0.5f * xx * (1.f - t * t) * c * (1.f + 3.f * a * x2);
}
__device__ __forceinline__ float gelu_only(float xx) {
  const float c = 0.7978845608028654f;
  const float a = 0.044715f;
  float u = c * (xx + a * xx * xx * xx);
  return 0.5f * xx * (1.f + tanhf(u));
}

// ---------------- conv3x3 + RMSNorm job (256 pixels) ----------------
__device__ __forceinline__ void conv_job(int job, const float* __restrict__ x,
                                         const float* smem, float* nk, float* nv) {
  int tid = threadIdx.x;
  int idx = job * 256 + tid;
  int t = idx / 784, hw = idx - t * 784;
  int h = hw / 28, w = hw - h * 28;
  const float* swk = smem;
  const float* swv = smem + 160;
  const float* sb  = smem + 320;
  float ak[4], av[4];
  #pragma unroll
  for (int c = 0; c < 4; ++c) { ak[c] = sb[c]; av[c] = sb[4 + c]; }
  const float* xt = x + (size_t)t * DM;
  for (int kh = 0; kh < 3; ++kh) {
    int ih = h + kh - 1;
    if (ih < 0 || ih >= 28) continue;
    for (int kw = 0; kw < 3; ++kw) {
      int iw = w + kw - 1;
      if (iw < 0 || iw >= 28) continue;
      int base = (kh * 3 + kw) * 16;
      #pragma unroll
      for (int ci = 0; ci < 4; ++ci) {
        float xv = xt[ci * 784 + ih * 28 + iw];
        #pragma unroll
        for (int co = 0; co < 4; ++co) {
          ak[co] += xv * swk[base + ci * 4 + co];
          av[co] += xv * swv[base + ci * 4 + co];
        }
      }
    }
  }
  float mk = (ak[0]*ak[0] + ak[1]*ak[1] + ak[2]*ak[2] + ak[3]*ak[3]) * 0.25f + 1e-6f;
  float mv = (av[0]*av[0] + av[1]*av[1] + av[2]*av[2] + av[3]*av[3]) * 0.25f + 1e-6f;
  float ik = 1.f / sqrtf(mk), iv = 1.f / sqrtf(mv);
  float4 ok = { ak[0]*ik*sb[8],  ak[1]*ik*sb[9],  ak[2]*ik*sb[10], ak[3]*ik*sb[11] };
  float4 ov = { av[0]*iv*sb[12], av[1]*iv*sb[13], av[2]*iv*sb[14], av[3]*iv*sb[15] };
  *(float4*)&nk[(size_t)idx * 4] = ok;
  *(float4*)&nv[(size_t)idx * 4] = ov;
}

// ---------------- A[64,512]@B[512,DM] tile -> atomicAdd into dst[64,DM] ----------------
__device__ __forceinline__ void mm_nn_atomic(
    const float* __restrict__ A, const float* __restrict__ B, float* dst,
    int bx, int by, float* smem) {
  float* As = smem;          // As[k*64+m]
  float* Bs = smem + 4096;   // Bs[k*64+n]
  int tid = threadIdx.x;
  int n0 = bx * 64, k0 = by * 64;
  {
    int m = tid >> 2, kb = (tid & 3) * 16;
    const float* Ap = A + (size_t)m * DH + k0 + kb;
    #pragma unroll
    for (int q = 0; q < 4; ++q) {
      float4 v = *(const float4*)(Ap + q * 4);
      As[(kb + q*4 + 0)*64 + m] = v.x;
      As[(kb + q*4 + 1)*64 + m] = v.y;
      As[(kb + q*4 + 2)*64 + m] = v.z;
      As[(kb + q*4 + 3)*64 + m] = v.w;
    }
    int kr = tid >> 4, nn = (tid & 15) * 4;
    #pragma unroll
    for (int q = 0; q < 4; ++q)
      *(float4*)&Bs[(kr + q*16)*64 + nn] = *(const float4*)(B + (size_t)(k0 + kr + q*16) * DM + n0 + nn);
  }
  __syncthreads();
  int tx = tid & 15, ty = tid >> 4;
  float acc[4][4] = {{0.f}};
  #pragma unroll 16
  for (int kk = 0; kk < 64; ++kk) {
    float4 a = *(const float4*)&As[kk*64 + ty * 4];
    float4 b = *(const float4*)&Bs[kk*64 + tx * 4];
    MICRO_4x4
  }
  __syncthreads();
  #pragma unroll
  for (int r = 0; r < 4; ++r) {
    float* pr = dst + (size_t)(ty*4 + r) * DM + n0 + tx * 4;
    atomicAdd(pr + 0, acc[r][0]);
    atomicAdd(pr + 1, acc[r][1]);
    atomicAdd(pr + 2, acc[r][2]);
    atomicAdd(pr + 3, acc[r][3]);
  }
}

// ---------------- E slice: (wc2*pred)[64,DM] @ W2^T tile -> Spart slice ----------------
__device__ __forceinline__ void mm_nt_slice(
    const float* __restrict__ pred, const float* __restrict__ W2c,
    float* Spart, float wc2, int bx, int by, float* smem) {
  float* As = smem;
  float* Bs = smem + 4096;
  int tid = threadIdx.x;
  int n0 = bx * 64, k0 = by * 64;
  {
    int m = tid >> 2, kb = (tid & 3) * 16;
    const float* Ap = pred + (size_t)m * DM + k0 + kb;
    const float* Bp = W2c + (size_t)(n0 + m) * DM + k0 + kb;
    #pragma unroll
    for (int q = 0; q < 4; ++q) {
      float4 va = *(const float4*)(Ap + q * 4);
      As[(kb + q*4 + 0)*64 + m] = va.x * wc2;
      As[(kb + q*4 + 1)*64 + m] = va.y * wc2;
      As[(kb + q*4 + 2)*64 + m] = va.z * wc2;
      As[(kb + q*4 + 3)*64 + m] = va.w * wc2;
      float4 vb = *(const float4*)(Bp + q * 4);
      Bs[(kb + q*4 + 0)*64 + m] = vb.x;
      Bs[(kb + q*4 + 1)*64 + m] = vb.y;
      Bs[(kb + q*4 + 2)*64 + m] = vb.z;
      Bs[(kb + q*4 + 3)*64 + m] = vb.w;
    }
  }
  __syncthreads();
  int tx = tid & 15, ty = tid >> 4;
  float acc[4][4] = {{0.f}};
  #pragma unroll 16
  for (int kk = 0; kk < 64; ++kk) {
    float4 a = *(const float4*)&As[kk*64 + ty * 4];
    float4 b = *(const float4*)&Bs[kk*64 + tx * 4];
    MICRO_4x4
  }
  __syncthreads();
  float* Cb = Spart + (size_t)by * 32768 + n0 + tx * 4;
  #pragma unroll
  for (int r = 0; r < 4; ++r) {
    float4 v = { acc[r][0], acc[r][1], acc[r][2], acc[r][3] };
    *(float4*)&Cb[(size_t)(ty*4 + r) * DH] = v;
  }
}

// ---------------- Cnew[P,Q] = Cold - A^T (bscale*B) ----------------
__device__ __forceinline__ void upd64s(
    const float* __restrict__ A, int P, const float* __restrict__ B, int Q,
    float bscale, const float* __restrict__ Cold, float* Cnew,
    int bx, int by, float* smem) {
  float* As = smem;
  float* Bs = smem + 4096;
  int tid = threadIdx.x;
  int q0 = bx * 64, p0 = by * 64;
  {
    int i = tid >> 4, c = (tid & 15) * 4;
    #pragma unroll
    for (int q = 0; q < 4; ++q) {
      *(float4*)&As[(i + q*16)*64 + c] = *(const float4*)(A + (size_t)(i + q*16) * P + p0 + c);
      float4 vb = *(const float4*)(B + (size_t)(i + q*16) * Q + q0 + c);
      vb.x *= bscale; vb.y *= bscale; vb.z *= bscale; vb.w *= bscale;
      *(float4*)&Bs[(i + q*16)*64 + c] = vb;
    }
  }
  __syncthreads();
  int tx = tid & 15, ty = tid >> 4;
  float acc[4][4] = {{0.f}};
  #pragma unroll 16
  for (int i = 0; i < 64; ++i) {
    float4 a = *(const float4*)&As[i*64 + ty * 4];
    float4 b = *(const float4*)&Bs[i*64 + tx * 4];
    MICRO_4x4
  }
  __syncthreads();
  #pragma unroll
  for (int r = 0; r < 4; ++r) {
    size_t off = (size_t)(p0 + ty*4 + r) * Q + q0 + tx*4;
    float4 co = *(const float4*)&Cold[off];
    float4 v = { co.x - acc[r][0], co.y - acc[r][1], co.z - acc[r][2], co.w - acc[r][3] };
    *(float4*)&Cnew[off] = v;
  }
}

// ---------------- KK pair: K_c K_j^T over one 448-wide k-split ----------------
__device__ __forceinline__ void kk_job(int p, int s, const float* __restrict__ nk,
                                       float* KKsl, float* smem) {
  float* As = smem;
  float* Bs = smem + 4096;
  int tid = threadIdx.x;
  int c = 0;
  while ((c + 1) * (c + 2) / 2 <= p) ++c;
  int j = p - c * (c + 1) / 2;
  const float* Kc = nk + (size_t)c * 64 * DM;
  const float* Kj = nk + (size_t)j * 64 * DM;
  int tx = tid & 15, ty = tid >> 4;
  int m = tid >> 2, kb = (tid & 3) * 16;
  float acc[4][4] = {{0.f}};
  for (int ks = 0; ks < 7; ++ks) {
    int kb0 = s * 448 + ks * 64;
    const float* Ap = Kc + (size_t)m * DM + kb0 + kb;
    const float* Bp = Kj + (size_t)m * DM + kb0 + kb;
    #pragma unroll
    for (int q = 0; q < 4; ++q) {
      float4 va = *(const float4*)(Ap + q * 4);
      As[(kb + q*4 + 0)*64 + m] = va.x;
      As[(kb + q*4 + 1)*64 + m] = va.y;
      As[(kb + q*4 + 2)*64 + m] = va.z;
      As[(kb + q*4 + 3)*64 + m] = va.w;
      float4 vb = *(const float4*)(Bp + q * 4);
      Bs[(kb + q*4 + 0)*64 + m] = vb.x;
      Bs[(kb + q*4 + 1)*64 + m] = vb.y;
      Bs[(kb + q*4 + 2)*64 + m] = vb.z;
      Bs[(kb + q*4 + 3)*64 + m] = vb.w;
    }
    __syncthreads();
    #pragma unroll 16
    for (int kk = 0; kk < 64; ++kk) {
      float4 a = *(const float4*)&As[kk*64 + ty * 4];
      float4 b = *(const float4*)&Bs[kk*64 + tx * 4];
      MICRO_4x4
    }
    __syncthreads();
  }
  float* dst = KKsl + ((size_t)p * 7 + s) * 4096;
  #pragma unroll
  for (int r = 0; r < 4; ++r) {
    float4 v = { acc[r][0], acc[r][1], acc[r][2], acc[r][3] };
    *(float4*)&dst[(ty*4 + r) * 64 + tx*4] = v;
  }
}

// ---------------- Hbase slices: K_all @ W1 ----------------
__device__ __forceinline__ void hb_job(int job, const float* __restrict__ nkA,
                                       const float* __restrict__ W1, float* Hb_sl,
                                       float* smem) {
  float* As = smem;
  float* Bs = smem + 4096;
  int tid = threadIdx.x;
  int n0 = (job & 7) * 64;
  int sK = (job >> 3) % 7;
  int m0 = (job / 56) * 64;
  int tx = tid & 15, ty = tid >> 4;
  int m = tid >> 2, kb = (tid & 3) * 16;
  int kr = tid >> 4, nn = (tid & 15) * 4;
  float acc[4][4] = {{0.f}};
  for (int ks = 0; ks < 7; ++ks) {
    int kb0 = sK * 448 + ks * 64;
    const float* Ap = nkA + (size_t)(m0 + m) * DM + kb0 + kb;
    #pragma unroll
    for (int q = 0; q < 4; ++q) {
      float4 v = *(const float4*)(Ap + q * 4);
      As[(kb + q*4 + 0)*64 + m] = v.x;
      As[(kb + q*4 + 1)*64 + m] = v.y;
      As[(kb + q*4 + 2)*64 + m] = v.z;
      As[(kb + q*4 + 3)*64 + m] = v.w;
      *(float4*)&Bs[(kr + q*16)*64 + nn] = *(const float4*)(W1 + (size_t)(kb0 + kr + q*16) * DH + n0 + nn);
    }
    __syncthreads();
    #pragma unroll 16
    for (int kk = 0; kk < 64; ++kk) {
      float4 a = *(const float4*)&As[kk*64 + ty * 4];
      float4 b = *(const float4*)&Bs[kk*64 + tx * 4];
      MICRO_4x4
    }
    __syncthreads();
  }
  #pragma unroll
  for (int r = 0; r < 4; ++r) {
    float4 v = { acc[r][0], acc[r][1], acc[r][2], acc[r][3] };
    *(float4*)&Hb_sl[((size_t)sK * 512 + m0 + ty*4 + r) * 512 + n0 + tx*4] = v;
  }
}

// ---------------- Hcorr[j] tile = KK @ Ew_j ----------------
__device__ __forceinline__ void hs_corr_job(
    const float* __restrict__ KK, const float* __restrict__ Ewj,
    float* dst, int bx, float* smem) {
  float* As = smem;          // As[i*64+m] = KK[m][i]
  float* Bs = smem + 4096;   // Bs[i*64+n]
  int tid = threadIdx.x;
  int n0 = bx * 64;
  {
    int m = tid >> 2, ib = (tid & 3) * 16;
    #pragma unroll
    for (int q = 0; q < 4; ++q) {
      float4 v = *(const float4*)(KK + m * 64 + ib + q * 4);
      As[(ib + q*4 + 0)*64 + m] = v.x;
      As[(ib + q*4 + 1)*64 + m] = v.y;
      As[(ib + q*4 + 2)*64 + m] = v.z;
      As[(ib + q*4 + 3)*64 + m] = v.w;
    }
    int kr = tid >> 4, nn = (tid & 15) * 4;
    #pragma unroll
    for (int q = 0; q < 4; ++q)
      *(float4*)&Bs[(kr + q*16)*64 + nn] = *(const float4*)(Ewj + (size_t)(kr + q*16) * DH + n0 + nn);
  }
  __syncthreads();
  int tx = tid & 15, ty = tid >> 4;
  float acc[4][4] = {{0.f}};
  #pragma unroll 16
  for (int kk = 0; kk < 64; ++kk) {
    float4 a = *(const float4*)&As[kk*64 + ty * 4];
    float4 b = *(const float4*)&Bs[kk*64 + tx * 4];
    MICRO_4x4
  }
  __syncthreads();
  #pragma unroll
  for (int r = 0; r < 4; ++r) {
    float4 v = { acc[r][0], acc[r][1], acc[r][2], acc[r][3] };
    *(float4*)&dst[(ty*4 + r) * DH + n0 + tx*4] = v;
  }
}

// ---------------- G2 tile: gelu(H - KKcc@Ew + b1n) ----------------
__device__ __forceinline__ void gelu2k_job(
    const float* __restrict__ KKcc, const float* __restrict__ Ew,
    const float* __restrict__ H, const float* __restrict__ b1n,
    float* G2, int n0, float* smem) {
  float* KKs = smem;         // 4096
  float* Ews = smem + 4096;  // 1024
  int tid = threadIdx.x;
  #pragma unroll
  for (int q = 0; q < 4; ++q) {
    int e4 = q * 256 + tid;
    *(float4*)&KKs[e4 * 4] = *(const float4*)(KKcc + e4 * 4);
  }
  {
    int i = tid >> 2, c4 = (tid & 3) * 4;
    *(float4*)&Ews[i * 16 + c4] = *(const float4*)(Ew + (size_t)i * DH + n0 + c4);
  }
  __syncthreads();
  #pragma unroll
  for (int q = 0; q < 4; ++q) {
    int e = q * 256 + tid;
    int mrow = e >> 4, cc = e & 15;
    float corr = 0.f;
    #pragma unroll 16
    for (int i = 0; i < 64; ++i) corr += KKs[mrow * 64 + i] * Ews[i * 16 + cc];
    float xx = H[mrow * DH + n0 + cc] - corr + b1n[n0 + cc];
    G2[mrow * DH + n0 + cc] = gelu_only(xx);
  }
  __syncthreads();
}

// ================= the mega kernel =================
__global__ __launch_bounds__(NTHR, 2) void mega(
    const float* __restrict__ x,
    const float* __restrict__ wk, const float* __restrict__ bk,
    const float* __restrict__ wv, const float* __restrict__ bv,
    const float* __restrict__ sk, const float* __restrict__ sv,
    const float* __restrict__ W1, const float* __restrict__ b1,
    const float* __restrict__ W2, const float* __restrict__ b2,
    float* __restrict__ out, float* __restrict__ ws, float wc2) {
  __shared__ float smem[8192];   // 32 KB, reused by every phase
  unsigned* bar = (unsigned*)ws;
  float* nk    = ws + 64;
  float* nv    = nk + 1605632;
  float* W2ws  = nv + 1605632;
  float* Spart = W2ws + 1605632;     // 49 x [64,512]
  float* Hb_sl = Spart + 1605632;    // 7 x 262144
  float* Hbase = Hb_sl + 1835008;    // [512,512]
  float* KKsl  = Hbase + 262144;     // 36 x 7 x 4096
  float* KKf   = KKsl + 1032192;     // 36 x 4096
  float* Hh    = KKf + 147456;       // 32768
  float* G     = Hh + 32768;         // 32768
  float* Gp    = G + 32768;          // 32768
  float* pred  = Gp + 32768;         // 200704
  float* Ewst  = pred + 200704;      // 8 x 32768
  float* Hcorr = Ewst + 262144;      // 7 x 32768
  float* b1ws  = Hcorr + 229376;     // 512
  float* b2ws  = b1ws + 512;         // 3136
  int tid = threadIdx.x;

  // ---- U0: conv + rmsnorm ----
  if (tid < 144) { smem[tid] = wk[tid]; smem[160 + tid] = wv[tid]; }
  if (tid < 4) {
    smem[320 + tid] = bk[tid]; smem[324 + tid] = bv[tid];
    smem[328 + tid] = sk[tid]; smem[332 + tid] = sv[tid];
  }
  __syncthreads();
  for (int job = blockIdx.x; job < 1568; job += GRID) conv_job(job, x, smem, nk, nv);
  gbar(bar);

  // ---- U1: KK pair slices + Hbase slices ----
  for (int job = blockIdx.x; job < 700; job += GRID) {
    if (job < 252) kk_job(job / 7, job % 7, nk, KKsl, smem);
    else           hb_job(job - 252, nk, W1, Hb_sl, smem);
  }
  gbar(bar);

  // ---- U2: reduce KK and Hbase slices ----
  for (int i = blockIdx.x * NTHR + tid; i < 147456; i += GRID * NTHR) {
    int pair = i >> 12, e = i & 4095;
    float s = 0.f;
    #pragma unroll
    for (int t = 0; t < 7; ++t) s += KKsl[((size_t)pair * 7 + t) * 4096 + e];
    KKf[i] = s;
  }
  for (int i = blockIdx.x * NTHR + tid; i < 262144; i += GRID * NTHR) {
    float s = 0.f;
    #pragma unroll
    for (int t = 0; t < 7; ++t) s += Hb_sl[(size_t)t * 262144 + i];
    Hbase[i] = s;
  }
  gbar(bar);

  // ---- chunk loop ----
  for (int ch = 0; ch < 8; ++ch) {
    const float* b1c = ch ? b1ws : b1;
    const float* b2c = ch ? b2ws : b2;
    const float* W2c = ch ? W2ws : W2;
    const float* V   = nv + (size_t)ch * 200704;
    float* Ewc = Ewst + (size_t)ch * 32768;
    int t0 = ch * 64;
    int tri = ch * (ch + 1) / 2;

    // S1: H/G/Gp + pred init (= b2 - V)
    for (int job = blockIdx.x; job < 912; job += GRID) {
      if (job < 128) {
        int j = job * 256 + tid;
        float s = Hbase[(size_t)ch * 32768 + j];
        for (int t = 0; t < ch; ++t) s -= Hcorr[(size_t)t * 32768 + j];
        Hh[j] = s;
        float g, gp;
        gelu_both(s + b1c[j & 511], g, gp);
        G[j] = g; Gp[j] = gp;
      } else {
        int idx = (job - 128) * 256 + tid;
        int col = idx % DM;
        pred[idx] = b2c[col] - V[idx];
      }
    }
    gbar(bar);

    // S2: pred += G @ W2c (atomic tiles)
    for (int job = blockIdx.x; job < 392; job += GRID)
      mm_nn_atomic(G, W2c, pred, job % 49, job / 49, smem);
    gbar(bar);

    // S3: E slices = (wc2*pred) @ W2c^T
    for (int job = blockIdx.x; job < 392; job += GRID)
      mm_nt_slice(pred, W2c, Spart, wc2, job & 7, job >> 3, smem);
    gbar(bar);

    // S4: W2 update || Ew + b1 update || b2 update
    for (int job = blockIdx.x; job < 569; job += GRID) {
      if (job < 392) {
        upd64s(G, DH, pred, DM, wc2, W2c, W2ws, job % 49, job / 49, smem);
      } else if (job < 520) {
        int n0 = (job - 392) * 4;
        int row = tid >> 2, c = tid & 3;
        int col = n0 + c;
        float s = 0.f;
        #pragma unroll
        for (int sl = 0; sl < 49; ++sl) s += Spart[(size_t)sl * 32768 + row * 512 + col];
        float ew = s * Gp[row * 512 + col];
        Ewc[row * 512 + col] = ew;
        smem[tid] = ew;
        __syncthreads();
        for (int off = 128; off >= 4; off >>= 1) {
          if (tid < off) smem[tid] += smem[tid + off];
          __syncthreads();
        }
        if (tid < 4) b1ws[n0 + tid] = b1c[n0 + tid] - smem[tid];
        __syncthreads();
      } else {
        int jb = job - 520;                 // < 49
        int c = tid & 63, rg = tid >> 6;
        int col = jb * 64 + c;
        float cs = 0.f;
        for (int rr = rg * 16; rr < rg * 16 + 16; ++rr)
          cs += pred[(size_t)rr * DM + col];
        smem[tid] = cs;
        __syncthreads();
        if (tid < 64) {
          float tot = smem[tid] + smem[tid + 64] + smem[tid + 128] + smem[tid + 192];
          b2ws[jb * 64 + tid] = b2c[jb * 64 + tid] - wc2 * tot;
        }
        __syncthreads();
      }
    }
    gbar(bar);

    // S5: G2 = gelu(H - KKcc@Ew + b1n)  ||  Hcorr for chunk ch+1  ||  out init = b2n
    for (int job = blockIdx.x; job < 880; job += GRID) {
      if (job < 32) {
        gelu2k_job(KKf + (size_t)(tri + ch) * 4096, Ewc, Hh, b1ws, G, job * 16, smem);
      } else if (job < 96) {
        int j2 = job - 32;
        if (ch < 7 && j2 < 8 * (ch + 1)) {
          int j = j2 >> 3, bxn = j2 & 7;
          int trin = (ch + 1) * (ch + 2) / 2;
          hs_corr_job(KKf + (size_t)(trin + j) * 4096, Ewst + (size_t)j * 32768,
                      Hcorr + (size_t)j * 32768, bxn, smem);
        }
      } else {
        int idx = (job - 96) * 256 + tid;   // < 200704
        out[(size_t)t0 * DM + idx] = b2ws[idx % DM];
      }
    }
    gbar(bar);

    // S6: out += G2 @ W2ws (atomic tiles)
    for (int job = blockIdx.x; job < 392; job += GRID)
      mm_nn_atomic(G, W2ws, out + (size_t)t0 * DM, job % 49, job / 49, smem);
    if (ch < 7) gbar(bar);
  }
}

extern "C" void kernel_launch(void* const* d_in, const int* in_sizes, int n_in,
                              void* d_out, int out_size, void* d_ws, size_t ws_size,
                              hipStream_t stream) {
  const float* x  = (const float*)d_in[0];
  const float* wk = (const float*)d_in[1];
  const float* bk = (const float*)d_in[2];
  const float* wv = (const float*)d_in[3];
  const float* bv = (const float*)d_in[4];
  const float* sk = (const float*)d_in[5];
  const float* sv = (const float*)d_in[6];
  const float* W1 = (const float*)d_in[7];
  const float* b1 = (const float*)d_in[8];
  const float* W2 = (const float*)d_in[9];
  const float* b2 = (const float*)d_in[10];
  float* out = (float*)d_out;
  float* ws  = (float*)d_ws;

  // zero the barrier region (ws is poisoned 0xAA before every launch)
  hipMemsetAsync(ws, 0, 256, stream);

  // weights[i] = ETA0 * ALPHA^i * (ALPHA^63 / ALPHA^i) = ETA0 * ALPHA^63 (constant)
  float wc2 = 2.0f * (float)(0.1 * pow(0.9, 63.0));

  mega<<<GRID, NTHR, 0, stream>>>(x, wk, bk, wv, bv, sk, sv, W1, b1, W2, b2, out, ws, wc2);
}

// Round 6
// 785.895 us; speedup vs baseline: 6.9339x; 6.9339x over previous
//
#include <hip/hip_runtime.h>
#include <math.h>

#define DM 3136
#define DH 512
#define NTHR 256

#define MICRO_4x4 \
    acc[0][0] += a.x*b.x; acc[0][1] += a.x*b.y; acc[0][2] += a.x*b.z; acc[0][3] += a.x*b.w; \
    acc[1][0] += a.y*b.x; acc[1][1] += a.y*b.y; acc[1][2] += a.y*b.z; acc[1][3] += a.y*b.w; \
    acc[2][0] += a.z*b.x; acc[2][1] += a.z*b.y; acc[2][2] += a.z*b.z; acc[2][3] += a.z*b.w; \
    acc[3][0] += a.w*b.x; acc[3][1] += a.w*b.y; acc[3][2] += a.w*b.z; acc[3][3] += a.w*b.w;

// ---------------- gelu ----------------
__device__ __forceinline__ void gelu_both(float xx, float& g, float& gp) {
  const float c = 0.7978845608028654f;
  const float a = 0.044715f;
  float x2 = xx * xx;
  float u = c * (xx + a * xx * x2);
  float t = tanhf(u);
  g  = 0.5f * xx * (1.f + t);
  gp = 0.5f * (1.f + t) + 0.5f * xx * (1.f - t * t) * c * (1.f + 3.f * a * x2);
}
__device__ __forceinline__ float gelu_only(float xx) {
  const float c = 0.7978845608028654f;
  const float a = 0.044715f;
  float u = c * (xx + a * xx * xx * xx);
  return 0.5f * xx * (1.f + tanhf(u));
}

// ---------------- conv3x3 + RMSNorm (proven R2) ----------------
__global__ __launch_bounds__(256) void conv_rms(
    const float* __restrict__ x,
    const float* __restrict__ wk, const float* __restrict__ bk,
    const float* __restrict__ wv, const float* __restrict__ bv,
    const float* __restrict__ sk, const float* __restrict__ sv,
    float* __restrict__ nk, float* __restrict__ nv) {
  __shared__ float swk[144], swv[144], sb[16];
  int tid = threadIdx.x;
  if (tid < 144) { swk[tid] = wk[tid]; swv[tid] = wv[tid]; }
  if (tid < 4) {
    sb[tid] = bk[tid]; sb[4 + tid] = bv[tid];
    sb[8 + tid] = sk[tid]; sb[12 + tid] = sv[tid];
  }
  __syncthreads();
  int idx = blockIdx.x * 256 + tid;
  int t = idx / 784, hw = idx - t * 784;
  int h = hw / 28, w = hw - h * 28;
  float ak[4], av[4];
  #pragma unroll
  for (int c = 0; c < 4; ++c) { ak[c] = sb[c]; av[c] = sb[4 + c]; }
  const float* xt = x + (size_t)t * DM;
  for (int kh = 0; kh < 3; ++kh) {
    int ih = h + kh - 1;
    if (ih < 0 || ih >= 28) continue;
    for (int kw = 0; kw < 3; ++kw) {
      int iw = w + kw - 1;
      if (iw < 0 || iw >= 28) continue;
      int base = (kh * 3 + kw) * 16;
      #pragma unroll
      for (int ci = 0; ci < 4; ++ci) {
        float xv = xt[ci * 784 + ih * 28 + iw];
        #pragma unroll
        for (int co = 0; co < 4; ++co) {
          ak[co] += xv * swk[base + ci * 4 + co];
          av[co] += xv * swv[base + ci * 4 + co];
        }
      }
    }
  }
  float mk = (ak[0]*ak[0] + ak[1]*ak[1] + ak[2]*ak[2] + ak[3]*ak[3]) * 0.25f + 1e-6f;
  float mv = (av[0]*av[0] + av[1]*av[1] + av[2]*av[2] + av[3]*av[3]) * 0.25f + 1e-6f;
  float ik = 1.f / sqrtf(mk), iv = 1.f / sqrtf(mv);
  float4 ok = { ak[0]*ik*sb[8],  ak[1]*ik*sb[9],  ak[2]*ik*sb[10], ak[3]*ik*sb[11] };
  float4 ov = { av[0]*iv*sb[12], av[1]*iv*sb[13], av[2]*iv*sb[14], av[3]*iv*sb[15] };
  *(float4*)&nk[(size_t)idx * 4] = ok;
  *(float4*)&nv[(size_t)idx * 4] = ov;
}

// ---------------- device GEMM bodies (proven R5) ----------------
__device__ __forceinline__ void mm_nn_atomic(
    const float* __restrict__ A, const float* __restrict__ B, float* dst,
    int bx, int by, float* smem) {
  float* As = smem;
  float* Bs = smem + 4096;
  int tid = threadIdx.x;
  int n0 = bx * 64, k0 = by * 64;
  {
    int m = tid >> 2, kb = (tid & 3) * 16;
    const float* Ap = A + (size_t)m * DH + k0 + kb;
    #pragma unroll
    for (int q = 0; q < 4; ++q) {
      float4 v = *(const float4*)(Ap + q * 4);
      As[(kb + q*4 + 0)*64 + m] = v.x;
      As[(kb + q*4 + 1)*64 + m] = v.y;
      As[(kb + q*4 + 2)*64 + m] = v.z;
      As[(kb + q*4 + 3)*64 + m] = v.w;
    }
    int kr = tid >> 4, nn = (tid & 15) * 4;
    #pragma unroll
    for (int q = 0; q < 4; ++q)
      *(float4*)&Bs[(kr + q*16)*64 + nn] = *(const float4*)(B + (size_t)(k0 + kr + q*16) * DM + n0 + nn);
  }
  __syncthreads();
  int tx = tid & 15, ty = tid >> 4;
  float acc[4][4] = {{0.f}};
  #pragma unroll 16
  for (int kk = 0; kk < 64; ++kk) {
    float4 a = *(const float4*)&As[kk*64 + ty * 4];
    float4 b = *(const float4*)&Bs[kk*64 + tx * 4];
    MICRO_4x4
  }
  #pragma unroll
  for (int r = 0; r < 4; ++r) {
    float* pr = dst + (size_t)(ty*4 + r) * DM + n0 + tx * 4;
    atomicAdd(pr + 0, acc[r][0]);
    atomicAdd(pr + 1, acc[r][1]);
    atomicAdd(pr + 2, acc[r][2]);
    atomicAdd(pr + 3, acc[r][3]);
  }
}

__device__ __forceinline__ void mm_nt_slice(
    const float* __restrict__ pred, const float* __restrict__ W2c,
    float* Spart, float wc2, int bx, int by, float* smem) {
  float* As = smem;
  float* Bs = smem + 4096;
  int tid = threadIdx.x;
  int n0 = bx * 64, k0 = by * 64;
  {
    int m = tid >> 2, kb = (tid & 3) * 16;
    const float* Ap = pred + (size_t)m * DM + k0 + kb;
    const float* Bp = W2c + (size_t)(n0 + m) * DM + k0 + kb;
    #pragma unroll
    for (int q = 0; q < 4; ++q) {
      float4 va = *(const float4*)(Ap + q * 4);
      As[(kb + q*4 + 0)*64 + m] = va.x * wc2;
      As[(kb + q*4 + 1)*64 + m] = va.y * wc2;
      As[(kb + q*4 + 2)*64 + m] = va.z * wc2;
      As[(kb + q*4 + 3)*64 + m] = va.w * wc2;
      float4 vb = *(const float4*)(Bp + q * 4);
      Bs[(kb + q*4 + 0)*64 + m] = vb.x;
      Bs[(kb + q*4 + 1)*64 + m] = vb.y;
      Bs[(kb + q*4 + 2)*64 + m] = vb.z;
      Bs[(kb + q*4 + 3)*64 + m] = vb.w;
    }
  }
  __syncthreads();
  int tx = tid & 15, ty = tid >> 4;
  float acc[4][4] = {{0.f}};
  #pragma unroll 16
  for (int kk = 0; kk < 64; ++kk) {
    float4 a = *(const float4*)&As[kk*64 + ty * 4];
    float4 b = *(const float4*)&Bs[kk*64 + tx * 4];
    MICRO_4x4
  }
  float* Cb = Spart + (size_t)by * 32768 + n0 + tx * 4;
  #pragma unroll
  for (int r = 0; r < 4; ++r) {
    float4 v = { acc[r][0], acc[r][1], acc[r][2], acc[r][3] };
    *(float4*)&Cb[(size_t)(ty*4 + r) * DH] = v;
  }
}

__device__ __forceinline__ void upd64s(
    const float* __restrict__ A, int P, const float* __restrict__ B, int Q,
    float bscale, const float* __restrict__ Cold, float* Cnew,
    int bx, int by, float* smem) {
  float* As = smem;
  float* Bs = smem + 4096;
  int tid = threadIdx.x;
  int q0 = bx * 64, p0 = by * 64;
  {
    int i = tid >> 4, c = (tid & 15) * 4;
    #pragma unroll
    for (int q = 0; q < 4; ++q) {
      *(float4*)&As[(i + q*16)*64 + c] = *(const float4*)(A + (size_t)(i + q*16) * P + p0 + c);
      float4 vb = *(const float4*)(B + (size_t)(i + q*16) * Q + q0 + c);
      vb.x *= bscale; vb.y *= bscale; vb.z *= bscale; vb.w *= bscale;
      *(float4*)&Bs[(i + q*16)*64 + c] = vb;
    }
  }
  __syncthreads();
  int tx = tid & 15, ty = tid >> 4;
  float acc[4][4] = {{0.f}};
  #pragma unroll 16
  for (int i = 0; i < 64; ++i) {
    float4 a = *(const float4*)&As[i*64 + ty * 4];
    float4 b = *(const float4*)&Bs[i*64 + tx * 4];
    MICRO_4x4
  }
  #pragma unroll
  for (int r = 0; r < 4; ++r) {
    size_t off = (size_t)(p0 + ty*4 + r) * Q + q0 + tx*4;
    float4 co = *(const float4*)&Cold[off];
    float4 v = { co.x - acc[r][0], co.y - acc[r][1], co.z - acc[r][2], co.w - acc[r][3] };
    *(float4*)&Cnew[off] = v;
  }
}

__device__ __forceinline__ void kk_job(int p, int s, const float* __restrict__ nk,
                                       float* KKsl, float* smem) {
  float* As = smem;
  float* Bs = smem + 4096;
  int tid = threadIdx.x;
  int c = 0;
  while ((c + 1) * (c + 2) / 2 <= p) ++c;
  int j = p - c * (c + 1) / 2;
  const float* Kc = nk + (size_t)c * 64 * DM;
  const float* Kj = nk + (size_t)j * 64 * DM;
  int tx = tid & 15, ty = tid >> 4;
  int m = tid >> 2, kb = (tid & 3) * 16;
  float acc[4][4] = {{0.f}};
  for (int ks = 0; ks < 7; ++ks) {
    int kb0 = s * 448 + ks * 64;
    const float* Ap = Kc + (size_t)m * DM + kb0 + kb;
    const float* Bp = Kj + (size_t)m * DM + kb0 + kb;
    #pragma unroll
    for (int q = 0; q < 4; ++q) {
      float4 va = *(const float4*)(Ap + q * 4);
      As[(kb + q*4 + 0)*64 + m] = va.x;
      As[(kb + q*4 + 1)*64 + m] = va.y;
      As[(kb + q*4 + 2)*64 + m] = va.z;
      As[(kb + q*4 + 3)*64 + m] = va.w;
      float4 vb = *(const float4*)(Bp + q * 4);
      Bs[(kb + q*4 + 0)*64 + m] = vb.x;
      Bs[(kb + q*4 + 1)*64 + m] = vb.y;
      Bs[(kb + q*4 + 2)*64 + m] = vb.z;
      Bs[(kb + q*4 + 3)*64 + m] = vb.w;
    }
    __syncthreads();
    #pragma unroll 16
    for (int kk = 0; kk < 64; ++kk) {
      float4 a = *(const float4*)&As[kk*64 + ty * 4];
      float4 b = *(const float4*)&Bs[kk*64 + tx * 4];
      MICRO_4x4
    }
    __syncthreads();
  }
  float* dst = KKsl + ((size_t)p * 7 + s) * 4096;
  #pragma unroll
  for (int r = 0; r < 4; ++r) {
    float4 v = { acc[r][0], acc[r][1], acc[r][2], acc[r][3] };
    *(float4*)&dst[(ty*4 + r) * 64 + tx*4] = v;
  }
}

__device__ __forceinline__ void hb_job(int job, const float* __restrict__ nkA,
                                       const float* __restrict__ W1, float* Hb_sl,
                                       float* smem) {
  float* As = smem;
  float* Bs = smem + 4096;
  int tid = threadIdx.x;
  int n0 = (job & 7) * 64;
  int sK = (job >> 3) % 7;
  int m0 = (job / 56) * 64;
  int tx = tid & 15, ty = tid >> 4;
  int m = tid >> 2, kb = (tid & 3) * 16;
  int kr = tid >> 4, nn = (tid & 15) * 4;
  float acc[4][4] = {{0.f}};
  for (int ks = 0; ks < 7; ++ks) {
    int kb0 = sK * 448 + ks * 64;
    const float* Ap = nkA + (size_t)(m0 + m) * DM + kb0 + kb;
    #pragma unroll
    for (int q = 0; q < 4; ++q) {
      float4 v = *(const float4*)(Ap + q * 4);
      As[(kb + q*4 + 0)*64 + m] = v.x;
      As[(kb + q*4 + 1)*64 + m] = v.y;
      As[(kb + q*4 + 2)*64 + m] = v.z;
      As[(kb + q*4 + 3)*64 + m] = v.w;
      *(float4*)&Bs[(kr + q*16)*64 + nn] = *(const float4*)(W1 + (size_t)(kb0 + kr + q*16) * DH + n0 + nn);
    }
    __syncthreads();
    #pragma unroll 16
    for (int kk = 0; kk < 64; ++kk) {
      float4 a = *(const float4*)&As[kk*64 + ty * 4];
      float4 b = *(const float4*)&Bs[kk*64 + tx * 4];
      MICRO_4x4
    }
    __syncthreads();
  }
  #pragma unroll
  for (int r = 0; r < 4; ++r) {
    float4 v = { acc[r][0], acc[r][1], acc[r][2], acc[r][3] };
    *(float4*)&Hb_sl[((size_t)sK * 512 + m0 + ty*4 + r) * 512 + n0 + tx*4] = v;
  }
}

__device__ __forceinline__ void hs_corr_job(
    const float* __restrict__ KK, const float* __restrict__ Ewj,
    float* dst, int bx, float* smem) {
  float* As = smem;
  float* Bs = smem + 4096;
  int tid = threadIdx.x;
  int n0 = bx * 64;
  {
    int m = tid >> 2, ib = (tid & 3) * 16;
    #pragma unroll
    for (int q = 0; q < 4; ++q) {
      float4 v = *(const float4*)(KK + m * 64 + ib + q * 4);
      As[(ib + q*4 + 0)*64 + m] = v.x;
      As[(ib + q*4 + 1)*64 + m] = v.y;
      As[(ib + q*4 + 2)*64 + m] = v.z;
      As[(ib + q*4 + 3)*64 + m] = v.w;
    }
    int kr = tid >> 4, nn = (tid & 15) * 4;
    #pragma unroll
    for (int q = 0; q < 4; ++q)
      *(float4*)&Bs[(kr + q*16)*64 + nn] = *(const float4*)(Ewj + (size_t)(kr + q*16) * DH + n0 + nn);
  }
  __syncthreads();
  int tx = tid & 15, ty = tid >> 4;
  float acc[4][4] = {{0.f}};
  #pragma unroll 16
  for (int kk = 0; kk < 64; ++kk) {
    float4 a = *(const float4*)&As[kk*64 + ty * 4];
    float4 b = *(const float4*)&Bs[kk*64 + tx * 4];
    MICRO_4x4
  }
  #pragma unroll
  for (int r = 0; r < 4; ++r) {
    float4 v = { acc[r][0], acc[r][1], acc[r][2], acc[r][3] };
    *(float4*)&dst[(ty*4 + r) * DH + n0 + tx*4] = v;
  }
}

__device__ __forceinline__ void gelu2k_job(
    const float* __restrict__ KKcc, const float* __restrict__ Ew,
    const float* __restrict__ H, const float* __restrict__ b1n,
    float* G2, int n0, float* smem) {
  float* KKs = smem;
  float* Ews = smem + 4096;
  int tid = threadIdx.x;
  #pragma unroll
  for (int q = 0; q < 4; ++q) {
    int e4 = q * 256 + tid;
    *(float4*)&KKs[e4 * 4] = *(const float4*)(KKcc + e4 * 4);
  }
  {
    int i = tid >> 2, c4 = (tid & 3) * 4;
    *(float4*)&Ews[i * 16 + c4] = *(const float4*)(Ew + (size_t)i * DH + n0 + c4);
  }
  __syncthreads();
  #pragma unroll
  for (int q = 0; q < 4; ++q) {
    int e = q * 256 + tid;
    int mrow = e >> 4, cc = e & 15;
    float corr = 0.f;
    #pragma unroll 16
    for (int i = 0; i < 64; ++i) corr += KKs[mrow * 64 + i] * Ews[i * 16 + cc];
    float xx = H[mrow * DH + n0 + cc] - corr + b1n[n0 + cc];
    G2[mrow * DH + n0 + cc] = gelu_only(xx);
  }
}

// ================= phase kernels (R5 phases, cut at barriers) =================
// U1: KK pair slices (252) + Hbase slices (448)
__global__ __launch_bounds__(256) void u1_kernel(
    const float* __restrict__ nk, const float* __restrict__ W1,
    float* __restrict__ KKsl, float* __restrict__ Hb_sl) {
  __shared__ float smem[8192];
  int job = blockIdx.x;
  if (job < 252) kk_job(job / 7, job % 7, nk, KKsl, smem);
  else           hb_job(job - 252, nk, W1, Hb_sl, smem);
}

// U2: reduce KK (147456) + Hbase (262144) slices
__global__ __launch_bounds__(256) void u2_kernel(
    const float* __restrict__ KKsl, const float* __restrict__ Hb_sl,
    float* __restrict__ KKf, float* __restrict__ Hbase) {
  int i = blockIdx.x * 256 + threadIdx.x;
  if (i < 147456) {
    int pair = i >> 12, e = i & 4095;
    float s = 0.f;
    #pragma unroll
    for (int t = 0; t < 7; ++t) s += KKsl[((size_t)pair * 7 + t) * 4096 + e];
    KKf[i] = s;
  } else {
    int j = i - 147456;   // < 262144
    float s = 0.f;
    #pragma unroll
    for (int t = 0; t < 7; ++t) s += Hb_sl[(size_t)t * 262144 + j];
    Hbase[j] = s;
  }
}

// K1: H/G/Gp (128) + pred init = b2 - V (784)
__global__ __launch_bounds__(256) void k1_kernel(
    const float* __restrict__ Hbase_c, const float* __restrict__ Hcorr, int nsl,
    const float* __restrict__ b1c, const float* __restrict__ b2c,
    const float* __restrict__ V,
    float* __restrict__ H, float* __restrict__ G, float* __restrict__ Gp,
    float* __restrict__ pred) {
  int job = blockIdx.x;
  int tid = threadIdx.x;
  if (job < 128) {
    int j = job * 256 + tid;
    float s = Hbase_c[j];
    for (int t = 0; t < nsl; ++t) s -= Hcorr[(size_t)t * 32768 + j];
    H[j] = s;
    float g, gp;
    gelu_both(s + b1c[j & 511], g, gp);
    G[j] = g; Gp[j] = gp;
  } else {
    int idx = (job - 128) * 256 + tid;
    pred[idx] = b2c[idx % DM] - V[idx];
  }
}

// K2: pred += G @ W2c (atomic, 392)
__global__ __launch_bounds__(256) void k2_kernel(
    const float* __restrict__ G, const float* __restrict__ W2c,
    float* __restrict__ pred) {
  __shared__ float smem[8192];
  mm_nn_atomic(G, W2c, pred, blockIdx.x % 49, blockIdx.x / 49, smem);
}

// K3: E slices = (wc2*pred)@W2c^T (392) + W2n = W2c - G^T(wc2*pred) (392)
__global__ __launch_bounds__(256) void k3_kernel(
    const float* __restrict__ pred, const float* __restrict__ W2c,
    const float* __restrict__ G, float* __restrict__ Spart,
    float* __restrict__ W2n, float wc2) {
  __shared__ float smem[8192];
  int job = blockIdx.x;
  if (job < 392) mm_nt_slice(pred, W2c, Spart, wc2, job & 7, job >> 3, smem);
  else           upd64s(G, DH, pred, DM, wc2, W2c, W2n, (job - 392) % 49, (job - 392) / 49, smem);
}

// K4: Ew = redE*Gp + b1n (128) + b2n = b2c - wc2*colsum(pred) (49)
__global__ __launch_bounds__(256) void k4_kernel(
    const float* __restrict__ Spart, const float* __restrict__ Gp,
    const float* __restrict__ pred,
    const float* __restrict__ b1c, const float* __restrict__ b2c,
    float* __restrict__ Ewc, float* __restrict__ b1n, float* __restrict__ b2n,
    float wc2) {
  __shared__ float smem[256];
  int job = blockIdx.x;
  int tid = threadIdx.x;
  if (job < 128) {
    int n0 = job * 4;
    int row = tid >> 2, c = tid & 3;
    int col = n0 + c;
    float s = 0.f;
    #pragma unroll
    for (int sl = 0; sl < 49; ++sl) s += Spart[(size_t)sl * 32768 + row * 512 + col];
    float ew = s * Gp[row * 512 + col];
    Ewc[row * 512 + col] = ew;
    smem[tid] = ew;
    __syncthreads();
    for (int off = 128; off >= 4; off >>= 1) {
      if (tid < off) smem[tid] += smem[tid + off];
      __syncthreads();
    }
    if (tid < 4) b1n[n0 + tid] = b1c[n0 + tid] - smem[tid];
  } else {
    int jb = job - 128;                 // < 49
    int c = tid & 63, rg = tid >> 6;
    int col = jb * 64 + c;
    float cs = 0.f;
    for (int rr = rg * 16; rr < rg * 16 + 16; ++rr)
      cs += pred[(size_t)rr * DM + col];
    smem[tid] = cs;
    __syncthreads();
    if (tid < 64) {
      float tot = smem[tid] + smem[tid + 64] + smem[tid + 128] + smem[tid + 192];
      b2n[jb * 64 + tid] = b2c[jb * 64 + tid] - wc2 * tot;
    }
  }
}

// K5: G2 (32) + Hcorr for next chunk (<=64) + out init = b2n (784)
__global__ __launch_bounds__(256) void k5_kernel(
    const float* __restrict__ KKf, int tri, int ch,
    const float* __restrict__ Ewst, const float* __restrict__ H,
    const float* __restrict__ b1n, const float* __restrict__ b2n,
    float* __restrict__ G, float* __restrict__ Hcorr,
    float* __restrict__ out_rows) {
  __shared__ float smem[8192];
  int job = blockIdx.x;
  int tid = threadIdx.x;
  const float* Ewc = Ewst + (size_t)ch * 32768;
  if (job < 32) {
    gelu2k_job(KKf + (size_t)(tri + ch) * 4096, Ewc, H, b1n, G, job * 16, smem);
  } else if (job < 96) {
    int j2 = job - 32;
    if (ch < 7 && j2 < 8 * (ch + 1)) {
      int j = j2 >> 3, bxn = j2 & 7;
      int trin = (ch + 1) * (ch + 2) / 2;
      hs_corr_job(KKf + (size_t)(trin + j) * 4096, Ewst + (size_t)j * 32768,
                  Hcorr + (size_t)j * 32768, bxn, smem);
    }
  } else {
    int idx = (job - 96) * 256 + tid;   // < 200704
    out_rows[idx] = b2n[idx % DM];
  }
}

// K6: out += G2 @ W2n (atomic, 392)
__global__ __launch_bounds__(256) void k6_kernel(
    const float* __restrict__ G2, const float* __restrict__ W2n,
    float* __restrict__ out_rows) {
  __shared__ float smem[8192];
  mm_nn_atomic(G2, W2n, out_rows, blockIdx.x % 49, blockIdx.x / 49, smem);
}

extern "C" void kernel_launch(void* const* d_in, const int* in_sizes, int n_in,
                              void* d_out, int out_size, void* d_ws, size_t ws_size,
                              hipStream_t stream) {
  const float* x  = (const float*)d_in[0];
  const float* wk = (const float*)d_in[1];
  const float* bk = (const float*)d_in[2];
  const float* wv = (const float*)d_in[3];
  const float* bv = (const float*)d_in[4];
  const float* sk = (const float*)d_in[5];
  const float* sv = (const float*)d_in[6];
  const float* W1 = (const float*)d_in[7];
  const float* b1 = (const float*)d_in[8];
  const float* W2 = (const float*)d_in[9];
  const float* b2 = (const float*)d_in[10];
  float* out = (float*)d_out;
  float* ws  = (float*)d_ws;

  // workspace layout (floats)
  float* nk    = ws;
  float* nv    = nk + 1605632;
  float* W2A   = nv + 1605632;
  float* W2B   = W2A + 1605632;
  float* Spart = W2B + 1605632;      // 49 x [64,512]
  float* Hb_sl = Spart + 1605632;    // 7 x 262144
  float* Hbase = Hb_sl + 1835008;    // [512,512]
  float* KKsl  = Hbase + 262144;     // 36 x 7 x 4096
  float* KKf   = KKsl + 1032192;     // 36 x 4096
  float* Hh    = KKf + 147456;       // 32768
  float* G     = Hh + 32768;         // 32768
  float* Gp    = G + 32768;          // 32768
  float* pred  = Gp + 32768;         // 200704
  float* Ewst  = pred + 200704;      // 8 x 32768
  float* Hcorr = Ewst + 262144;      // 7 x 32768
  float* b1ws  = Hcorr + 229376;     // 512
  float* b2ws  = b1ws + 512;         // 3136
  float* W2buf[2] = { W2A, W2B };

  // weights[i] = ETA0 * ALPHA^i * (ALPHA^63 / ALPHA^i) = ETA0 * ALPHA^63 (constant)
  float wc2 = 2.0f * (float)(0.1 * pow(0.9, 63.0));

  conv_rms<<<1568, 256, 0, stream>>>(x, wk, bk, wv, bv, sk, sv, nk, nv);
  u1_kernel<<<700, 256, 0, stream>>>(nk, W1, KKsl, Hb_sl);
  u2_kernel<<<1600, 256, 0, stream>>>(KKsl, Hb_sl, KKf, Hbase);

  for (int ch = 0; ch < 8; ++ch) {
    const float* V   = nv + (size_t)ch * 200704;
    const float* b1c = ch ? b1ws : b1;
    const float* b2c = ch ? b2ws : b2;
    const float* W2c = ch ? W2buf[(ch - 1) & 1] : W2;
    float* W2n = W2buf[ch & 1];
    float* Ewc = Ewst + (size_t)ch * 32768;
    int tri = ch * (ch + 1) / 2;
    float* out_rows = out + (size_t)ch * 64 * DM;

    k1_kernel<<<912, 256, 0, stream>>>(Hbase + (size_t)ch * 32768, Hcorr, ch,
                                       b1c, b2c, V, Hh, G, Gp, pred);
    k2_kernel<<<392, 256, 0, stream>>>(G, W2c, pred);
    k3_kernel<<<784, 256, 0, stream>>>(pred, W2c, G, Spart, W2n, wc2);
    k4_kernel<<<177, 256, 0, stream>>>(Spart, Gp, pred, b1c, b2c,
                                       Ewc, b1ws, b2ws, wc2);
    k5_kernel<<<880, 256, 0, stream>>>(KKf, tri, ch, Ewst, Hh, b1ws, b2ws,
                                       G, Hcorr, out_rows);
    k6_kernel<<<392, 256, 0, stream>>>(G, W2n, out_rows);
  }
}

// Round 7
// 614.041 us; speedup vs baseline: 8.8746x; 1.2799x over previous
//
#include <hip/hip_runtime.h>
#include <math.h>

#define DM 3136
#define DH 512

#define MICRO_4x4 \
    acc[0][0] += a.x*b.x; acc[0][1] += a.x*b.y; acc[0][2] += a.x*b.z; acc[0][3] += a.x*b.w; \
    acc[1][0] += a.y*b.x; acc[1][1] += a.y*b.y; acc[1][2] += a.y*b.z; acc[1][3] += a.y*b.w; \
    acc[2][0] += a.z*b.x; acc[2][1] += a.z*b.y; acc[2][2] += a.z*b.z; acc[2][3] += a.z*b.w; \
    acc[3][0] += a.w*b.x; acc[3][1] += a.w*b.y; acc[3][2] += a.w*b.z; acc[3][3] += a.w*b.w;

// ---------------- gelu ----------------
__device__ __forceinline__ void gelu_both(float xx, float& g, float& gp) {
  const float c = 0.7978845608028654f;
  const float a = 0.044715f;
  float x2 = xx * xx;
  float u = c * (xx + a * xx * x2);
  float t = tanhf(u);
  g  = 0.5f * xx * (1.f + t);
  gp = 0.5f * (1.f + t) + 0.5f * xx * (1.f - t * t) * c * (1.f + 3.f * a * x2);
}
__device__ __forceinline__ float gelu_only(float xx) {
  const float c = 0.7978845608028654f;
  const float a = 0.044715f;
  float u = c * (xx + a * xx * xx * xx);
  return 0.5f * xx * (1.f + tanhf(u));
}

// ---------------- conv3x3 + RMSNorm (proven R2) ----------------
__global__ __launch_bounds__(256) void conv_rms(
    const float* __restrict__ x,
    const float* __restrict__ wk, const float* __restrict__ bk,
    const float* __restrict__ wv, const float* __restrict__ bv,
    const float* __restrict__ sk, const float* __restrict__ sv,
    float* __restrict__ nk, float* __restrict__ nv) {
  __shared__ float swk[144], swv[144], sb[16];
  int tid = threadIdx.x;
  if (tid < 144) { swk[tid] = wk[tid]; swv[tid] = wv[tid]; }
  if (tid < 4) {
    sb[tid] = bk[tid]; sb[4 + tid] = bv[tid];
    sb[8 + tid] = sk[tid]; sb[12 + tid] = sv[tid];
  }
  __syncthreads();
  int idx = blockIdx.x * 256 + tid;
  int t = idx / 784, hw = idx - t * 784;
  int h = hw / 28, w = hw - h * 28;
  float ak[4], av[4];
  #pragma unroll
  for (int c = 0; c < 4; ++c) { ak[c] = sb[c]; av[c] = sb[4 + c]; }
  const float* xt = x + (size_t)t * DM;
  for (int kh = 0; kh < 3; ++kh) {
    int ih = h + kh - 1;
    if (ih < 0 || ih >= 28) continue;
    for (int kw = 0; kw < 3; ++kw) {
      int iw = w + kw - 1;
      if (iw < 0 || iw >= 28) continue;
      int base = (kh * 3 + kw) * 16;
      #pragma unroll
      for (int ci = 0; ci < 4; ++ci) {
        float xv = xt[ci * 784 + ih * 28 + iw];
        #pragma unroll
        for (int co = 0; co < 4; ++co) {
          ak[co] += xv * swk[base + ci * 4 + co];
          av[co] += xv * swv[base + ci * 4 + co];
        }
      }
    }
  }
  float mk = (ak[0]*ak[0] + ak[1]*ak[1] + ak[2]*ak[2] + ak[3]*ak[3]) * 0.25f + 1e-6f;
  float mv = (av[0]*av[0] + av[1]*av[1] + av[2]*av[2] + av[3]*av[3]) * 0.25f + 1e-6f;
  float ik = 1.f / sqrtf(mk), iv = 1.f / sqrtf(mv);
  float4 ok = { ak[0]*ik*sb[8],  ak[1]*ik*sb[9],  ak[2]*ik*sb[10], ak[3]*ik*sb[11] };
  float4 ov = { av[0]*iv*sb[12], av[1]*iv*sb[13], av[2]*iv*sb[14], av[3]*iv*sb[15] };
  *(float4*)&nk[(size_t)idx * 4] = ok;
  *(float4*)&nv[(size_t)idx * 4] = ov;
}

// ---------------- mm64_nn: A[64,K]@B -> split-K slices (proven R2/R4) ----------------
__global__ __launch_bounds__(256) void mm64_nn(
    const float* __restrict__ A, int lda,
    const float* __restrict__ B, int ldb,
    float* __restrict__ Cp, int ldc) {
  __shared__ float As[4096];
  __shared__ float Bs[4096];
  int tid = threadIdx.x;
  int n0 = blockIdx.x * 64;
  int k0 = blockIdx.y * 64;
  {
    int m  = tid >> 2;
    int kb = (tid & 3) * 16;
    const float* Ap = A + (size_t)m * lda + k0 + kb;
    #pragma unroll
    for (int q = 0; q < 4; ++q) {
      float4 v = *(const float4*)(Ap + q * 4);
      As[(kb + q*4 + 0)*64 + m] = v.x;
      As[(kb + q*4 + 1)*64 + m] = v.y;
      As[(kb + q*4 + 2)*64 + m] = v.z;
      As[(kb + q*4 + 3)*64 + m] = v.w;
    }
    int kr = tid >> 4;
    int nn = (tid & 15) * 4;
    #pragma unroll
    for (int q = 0; q < 4; ++q)
      *(float4*)&Bs[(kr + q*16)*64 + nn] = *(const float4*)(B + (size_t)(k0 + kr + q*16) * ldb + n0 + nn);
  }
  __syncthreads();
  int tx = tid & 15, ty = tid >> 4;
  float acc[4][4] = {{0.f}};
  #pragma unroll 16
  for (int kk = 0; kk < 64; ++kk) {
    float4 a = *(const float4*)&As[kk*64 + ty * 4];
    float4 b = *(const float4*)&Bs[kk*64 + tx * 4];
    MICRO_4x4
  }
  float* Cb = Cp + (size_t)blockIdx.y * 64 * ldc + n0 + tx * 4;
  #pragma unroll
  for (int r = 0; r < 4; ++r) {
    float4 v = { acc[r][0], acc[r][1], acc[r][2], acc[r][3] };
    *(float4*)&Cb[(size_t)(ty * 4 + r) * ldc] = v;
  }
}

// ---------------- mm64_nt: A[64,K]@B^T, B [N,K] row-major (proven R2/R4) ----------------
__global__ __launch_bounds__(256) void mm64_nt(
    const float* __restrict__ A, int lda,
    const float* __restrict__ B, int ldb,
    float* __restrict__ Cp, int ldc) {
  __shared__ float As[4096];
  __shared__ float Bs[4096];
  int tid = threadIdx.x;
  int n0 = blockIdx.x * 64;
  int k0 = blockIdx.y * 64;
  {
    int m  = tid >> 2;
    int kb = (tid & 3) * 16;
    const float* Ap = A + (size_t)m * lda + k0 + kb;
    const float* Bp = B + (size_t)(n0 + m) * ldb + k0 + kb;
    #pragma unroll
    for (int q = 0; q < 4; ++q) {
      float4 va = *(const float4*)(Ap + q * 4);
      As[(kb + q*4 + 0)*64 + m] = va.x;
      As[(kb + q*4 + 1)*64 + m] = va.y;
      As[(kb + q*4 + 2)*64 + m] = va.z;
      As[(kb + q*4 + 3)*64 + m] = va.w;
      float4 vb = *(const float4*)(Bp + q * 4);
      Bs[(kb + q*4 + 0)*64 + m] = vb.x;
      Bs[(kb + q*4 + 1)*64 + m] = vb.y;
      Bs[(kb + q*4 + 2)*64 + m] = vb.z;
      Bs[(kb + q*4 + 3)*64 + m] = vb.w;
    }
  }
  __syncthreads();
  int tx = tid & 15, ty = tid >> 4;
  float acc[4][4] = {{0.f}};
  #pragma unroll 16
  for (int kk = 0; kk < 64; ++kk) {
    float4 a = *(const float4*)&As[kk*64 + ty * 4];
    float4 b = *(const float4*)&Bs[kk*64 + tx * 4];
    MICRO_4x4
  }
  float* Cb = Cp + (size_t)blockIdx.y * 64 * ldc + n0 + tx * 4;
  #pragma unroll
  for (int r = 0; r < 4; ++r) {
    float4 v = { acc[r][0], acc[r][1], acc[r][2], acc[r][3] };
    *(float4*)&Cb[(size_t)(ty * 4 + r) * ldc] = v;
  }
}

// ---------------- upd64 device body: Cnew = Cold - A^T B (proven R3/R4) ----------------
__device__ __forceinline__ void upd64_dev(
    const float* __restrict__ A, int P,
    const float* __restrict__ B, int Q,
    const float* __restrict__ Cold, float* __restrict__ Cnew,
    int bx, int by, float* smem) {
  float* As = smem;
  float* Bs = smem + 4096;
  int tid = threadIdx.x;
  int q0 = bx * 64;
  int p0 = by * 64;
  {
    int i = tid >> 4;
    int c = (tid & 15) * 4;
    #pragma unroll
    for (int q = 0; q < 4; ++q) {
      *(float4*)&As[(i + q*16)*64 + c] = *(const float4*)(A + (size_t)(i + q*16) * P + p0 + c);
      *(float4*)&Bs[(i + q*16)*64 + c] = *(const float4*)(B + (size_t)(i + q*16) * Q + q0 + c);
    }
  }
  __syncthreads();
  int tx = tid & 15, ty = tid >> 4;
  float acc[4][4] = {{0.f}};
  #pragma unroll 16
  for (int i = 0; i < 64; ++i) {
    float4 a = *(const float4*)&As[i*64 + ty * 4];
    float4 b = *(const float4*)&Bs[i*64 + tx * 4];
    MICRO_4x4
  }
  #pragma unroll
  for (int r = 0; r < 4; ++r) {
    size_t off = (size_t)(p0 + ty*4 + r) * Q + q0 + tx*4;
    float4 co = *(const float4*)&Cold[off];
    float4 v = { co.x - acc[r][0], co.y - acc[r][1], co.z - acc[r][2], co.w - acc[r][3] };
    *(float4*)&Cnew[off] = v;
  }
}

// ---------------- u1: single-64k-slice jobs for KK pairs and Hbase ----------------
__device__ __forceinline__ void kk_slice(int p, int s, const float* __restrict__ nk,
                                         float* __restrict__ KKsl, float* smem) {
  float* As = smem;
  float* Bs = smem + 4096;
  int tid = threadIdx.x;
  int c = 0;
  while ((c + 1) * (c + 2) / 2 <= p) ++c;
  int j = p - c * (c + 1) / 2;
  const float* A = nk + (size_t)c * 64 * DM;
  const float* B = nk + (size_t)j * 64 * DM;
  int k0 = s * 64;
  {
    int m  = tid >> 2;
    int kb = (tid & 3) * 16;
    const float* Ap = A + (size_t)m * DM + k0 + kb;
    const float* Bp = B + (size_t)m * DM + k0 + kb;
    #pragma unroll
    for (int q = 0; q < 4; ++q) {
      float4 va = *(const float4*)(Ap + q * 4);
      As[(kb + q*4 + 0)*64 + m] = va.x;
      As[(kb + q*4 + 1)*64 + m] = va.y;
      As[(kb + q*4 + 2)*64 + m] = va.z;
      As[(kb + q*4 + 3)*64 + m] = va.w;
      float4 vb = *(const float4*)(Bp + q * 4);
      Bs[(kb + q*4 + 0)*64 + m] = vb.x;
      Bs[(kb + q*4 + 1)*64 + m] = vb.y;
      Bs[(kb + q*4 + 2)*64 + m] = vb.z;
      Bs[(kb + q*4 + 3)*64 + m] = vb.w;
    }
  }
  __syncthreads();
  int tx = tid & 15, ty = tid >> 4;
  float acc[4][4] = {{0.f}};
  #pragma unroll 16
  for (int kk = 0; kk < 64; ++kk) {
    float4 a = *(const float4*)&As[kk*64 + ty * 4];
    float4 b = *(const float4*)&Bs[kk*64 + tx * 4];
    MICRO_4x4
  }
  float* dst = KKsl + ((size_t)p * 49 + s) * 4096;
  #pragma unroll
  for (int r = 0; r < 4; ++r) {
    float4 v = { acc[r][0], acc[r][1], acc[r][2], acc[r][3] };
    *(float4*)&dst[(ty*4 + r) * 64 + tx*4] = v;
  }
}

__device__ __forceinline__ void hb_slice(int jb, const float* __restrict__ nkA,
                                         const float* __restrict__ W1,
                                         float* __restrict__ Hb_sl, float* smem) {
  float* As = smem;
  float* Bs = smem + 4096;
  int tid = threadIdx.x;
  int s  = jb % 49;
  int nt = (jb / 49) % 8;
  int mt = jb / 392;
  int n0 = nt * 64;
  int m0 = mt * 64;
  int k0 = s * 64;
  {
    int m  = tid >> 2;
    int kb = (tid & 3) * 16;
    const float* Ap = nkA + (size_t)(m0 + m) * DM + k0 + kb;
    #pragma unroll
    for (int q = 0; q < 4; ++q) {
      float4 v = *(const float4*)(Ap + q * 4);
      As[(kb + q*4 + 0)*64 + m] = v.x;
      As[(kb + q*4 + 1)*64 + m] = v.y;
      As[(kb + q*4 + 2)*64 + m] = v.z;
      As[(kb + q*4 + 3)*64 + m] = v.w;
    }
    int kr = tid >> 4;
    int nn = (tid & 15) * 4;
    #pragma unroll
    for (int q = 0; q < 4; ++q)
      *(float4*)&Bs[(kr + q*16)*64 + nn] = *(const float4*)(W1 + (size_t)(k0 + kr + q*16) * DH + n0 + nn);
  }
  __syncthreads();
  int tx = tid & 15, ty = tid >> 4;
  float acc[4][4] = {{0.f}};
  #pragma unroll 16
  for (int kk = 0; kk < 64; ++kk) {
    float4 a = *(const float4*)&As[kk*64 + ty * 4];
    float4 b = *(const float4*)&Bs[kk*64 + tx * 4];
    MICRO_4x4
  }
  float* dst = Hb_sl + (size_t)s * 262144;
  #pragma unroll
  for (int r = 0; r < 4; ++r) {
    float4 v = { acc[r][0], acc[r][1], acc[r][2], acc[r][3] };
    *(float4*)&dst[(size_t)(m0 + ty*4 + r) * 512 + n0 + tx*4] = v;
  }
}

__global__ __launch_bounds__(256) void u1_kernel(
    const float* __restrict__ nk, const float* __restrict__ W1,
    float* __restrict__ KKsl, float* __restrict__ Hb_sl) {
  __shared__ float smem[8192];
  int job = blockIdx.x;
  if (job < 1764) kk_slice(job / 49, job % 49, nk, KKsl, smem);
  else            hb_slice(job - 1764, nk, W1, Hb_sl, smem);
}

// u2: KKf (36x4096, sum 49) + Hbase (262144, sum 49)
__global__ __launch_bounds__(256) void u2_kernel(
    const float* __restrict__ KKsl, const float* __restrict__ Hb_sl,
    float* __restrict__ KKf, float* __restrict__ Hbase) {
  int i = blockIdx.x * 256 + threadIdx.x;
  if (i < 147456) {
    int pair = i >> 12, e = i & 4095;
    float s = 0.f;
    for (int t = 0; t < 49; ++t) s += KKsl[((size_t)pair * 49 + t) * 4096 + e];
    KKf[i] = s;
  } else {
    int j = i - 147456;   // < 262144
    float s = 0.f;
    for (int t = 0; t < 49; ++t) s += Hb_sl[(size_t)t * 262144 + j];
    Hbase[j] = s;
  }
}

// ---------------- hred_gelu (R4): H = Hbase_c - sum(corr); G, Gp ----------------
__global__ __launch_bounds__(256) void hred_gelu(
    const float* __restrict__ Hb_c, const float* __restrict__ Hcorr, int nsl,
    const float* __restrict__ b1,
    float* __restrict__ H, float* __restrict__ G, float* __restrict__ Gp) {
  int j = blockIdx.x * 256 + threadIdx.x;
  float s = Hb_c[j];
  for (int t = 0; t < nsl; ++t) s -= Hcorr[(size_t)t * 32768 + j];
  H[j] = s;
  float xx = s + b1[j & 511];
  float g, gp;
  gelu_both(xx, g, gp);
  G[j] = g; Gp[j] = gp;
}

// ---------------- red_Db2 (R4): Dw + b2 update, grid 49 ----------------
__global__ __launch_bounds__(256) void red_Db2(
    const float* __restrict__ Dp, const float* __restrict__ b2c,
    const float* __restrict__ V, float wc2,
    float* __restrict__ Dw, float* __restrict__ b2n) {
  __shared__ float sm[256];
  int tid = threadIdx.x;
  int col = blockIdx.x * 64 + (tid & 63);
  int r0 = (tid >> 6) * 16;
  float bb = b2c[col];
  float cs = 0.f;
  for (int rr = 0; rr < 16; ++rr) {
    size_t off = (size_t)(r0 + rr) * DM + col;
    float s = 0.f;
    #pragma unroll
    for (int t = 0; t < 8; ++t) s += Dp[(size_t)t * 200704 + off];
    float d = wc2 * (s + bb - V[off]);
    Dw[off] = d;
    cs += d;
  }
  sm[tid] = cs;
  __syncthreads();
  if (tid < 64) {
    float tot = sm[tid] + sm[tid + 64] + sm[tid + 128] + sm[tid + 192];
    b2n[blockIdx.x * 64 + tid] = b2c[blockIdx.x * 64 + tid] - tot;
  }
}

// ---------------- comb5 (R4): upd64-W2 (0..391) || red_E + b1 update (392..519) ----------------
__global__ __launch_bounds__(256) void comb5(
    const float* __restrict__ G, const float* __restrict__ Dw,
    const float* __restrict__ W2old, float* __restrict__ W2new,
    const float* __restrict__ Esl, const float* __restrict__ Gp,
    float* __restrict__ Ew, const float* __restrict__ b1old, float* __restrict__ b1new) {
  __shared__ float smem[8192];
  int li = blockIdx.x;
  int tid = threadIdx.x;
  if (li < 392) {
    upd64_dev(G, DH, Dw, DM, W2old, W2new, li % 49, li / 49, smem);
  } else {
    int li2 = li - 392;
    int n0 = li2 * 4;
    int row = tid >> 2, c = tid & 3;
    int col = n0 + c;
    float s = 0.f;
    #pragma unroll
    for (int sl = 0; sl < 49; ++sl) s += Esl[(size_t)sl * 32768 + row * 512 + col];
    float ew = s * Gp[row * 512 + col];
    Ew[row * 512 + col] = ew;
    smem[tid] = ew;
    __syncthreads();
    for (int off = 128; off >= 4; off >>= 1) {
      if (tid < off) smem[tid] += smem[tid + off];
      __syncthreads();
    }
    if (tid < 4) b1new[n0 + tid] = b1old[n0 + tid] - smem[tid];
  }
}

// ---------------- g2h: gelu2k (32) || hs_corr for next chunk (<=64) ----------------
__device__ __forceinline__ void gelu2k_job(
    const float* __restrict__ KKcc, const float* __restrict__ Ew,
    const float* __restrict__ H, const float* __restrict__ b1n,
    float* __restrict__ G2, int n0, float* smem) {
  float* KKs = smem;
  float* Ews = smem + 4096;
  int tid = threadIdx.x;
  #pragma unroll
  for (int q = 0; q < 4; ++q) {
    int e4 = q * 256 + tid;
    *(float4*)&KKs[e4 * 4] = *(const float4*)(KKcc + e4 * 4);
  }
  {
    int i = tid >> 2, c4 = (tid & 3) * 4;
    *(float4*)&Ews[i * 16 + c4] = *(const float4*)(Ew + (size_t)i * DH + n0 + c4);
  }
  __syncthreads();
  #pragma unroll
  for (int q = 0; q < 4; ++q) {
    int e = q * 256 + tid;
    int mrow = e >> 4, cc = e & 15;
    float corr = 0.f;
    #pragma unroll 16
    for (int i = 0; i < 64; ++i) corr += KKs[mrow * 64 + i] * Ews[i * 16 + cc];
    float xx = H[mrow * DH + n0 + cc] - corr + b1n[n0 + cc];
    G2[mrow * DH + n0 + cc] = gelu_only(xx);
  }
}

__device__ __forceinline__ void hs_corr_job(
    const float* __restrict__ KK, const float* __restrict__ Ewj,
    float* __restrict__ dst, int bx, float* smem) {
  float* As = smem;
  float* Bs = smem + 4096;
  int tid = threadIdx.x;
  int n0 = bx * 64;
  {
    int m = tid >> 2, ib = (tid & 3) * 16;
    #pragma unroll
    for (int q = 0; q < 4; ++q) {
      float4 v = *(const float4*)(KK + m * 64 + ib + q * 4);
      As[(ib + q*4 + 0)*64 + m] = v.x;
      As[(ib + q*4 + 1)*64 + m] = v.y;
      As[(ib + q*4 + 2)*64 + m] = v.z;
      As[(ib + q*4 + 3)*64 + m] = v.w;
    }
    int kr = tid >> 4, nn = (tid & 15) * 4;
    #pragma unroll
    for (int q = 0; q < 4; ++q)
      *(float4*)&Bs[(kr + q*16)*64 + nn] = *(const float4*)(Ewj + (size_t)(kr + q*16) * DH + n0 + nn);
  }
  __syncthreads();
  int tx = tid & 15, ty = tid >> 4;
  float acc[4][4] = {{0.f}};
  #pragma unroll 16
  for (int kk = 0; kk < 64; ++kk) {
    float4 a = *(const float4*)&As[kk*64 + ty * 4];
    float4 b = *(const float4*)&Bs[kk*64 + tx * 4];
    MICRO_4x4
  }
  #pragma unroll
  for (int r = 0; r < 4; ++r) {
    float4 v = { acc[r][0], acc[r][1], acc[r][2], acc[r][3] };
    *(float4*)&dst[(ty*4 + r) * DH + n0 + tx*4] = v;
  }
}

__global__ __launch_bounds__(256) void g2h_kernel(
    const float* __restrict__ KKf, int tri, int ch,
    const float* __restrict__ Ewst, const float* __restrict__ H,
    const float* __restrict__ b1n,
    float* __restrict__ G, float* __restrict__ Hcorr) {
  __shared__ float smem[8192];
  int job = blockIdx.x;
  if (job < 32) {
    gelu2k_job(KKf + (size_t)(tri + ch) * 4096, Ewst + (size_t)ch * 32768,
               H, b1n, G, job * 16, smem);
  } else if (ch < 7) {
    int j2 = job - 32;
    if (j2 < 8 * (ch + 1)) {
      int j = j2 >> 3, bx = j2 & 7;
      int trin = (ch + 1) * (ch + 2) / 2;
      hs_corr_job(KKf + (size_t)(trin + j) * 4096, Ewst + (size_t)j * 32768,
                  Hcorr + (size_t)j * 32768, bx, smem);
    }
  }
}

// ---------------- redY_hg: out rows (784) || hred_gelu for next chunk (128) ----------------
__global__ __launch_bounds__(256) void redy_hg(
    const float* __restrict__ Sp, const float* __restrict__ b2n,
    float* __restrict__ out, int t0,
    int do_hg, const float* __restrict__ Hbase_n, const float* __restrict__ Hcorr,
    int nsl, const float* __restrict__ b1n,
    float* __restrict__ H, float* __restrict__ G, float* __restrict__ Gp) {
  int job = blockIdx.x, tid = threadIdx.x;
  if (job < 784) {
    int j = job * 256 + tid;
    float s = 0.f;
    #pragma unroll
    for (int t = 0; t < 8; ++t) s += Sp[(size_t)t * 200704 + j];
    int i = j / DM;
    int d = j - i * DM;
    out[(size_t)t0 * DM + j] = s + b2n[d];
  } else if (do_hg) {
    int j = (job - 784) * 256 + tid;   // < 32768
    float s = Hbase_n[j];
    for (int t = 0; t < nsl; ++t) s -= Hcorr[(size_t)t * 32768 + j];
    H[j] = s;
    float g, gp;
    gelu_both(s + b1n[j & 511], g, gp);
    G[j] = g; Gp[j] = gp;
  }
}

extern "C" void kernel_launch(void* const* d_in, const int* in_sizes, int n_in,
                              void* d_out, int out_size, void* d_ws, size_t ws_size,
                              hipStream_t stream) {
  const float* x  = (const float*)d_in[0];
  const float* wk = (const float*)d_in[1];
  const float* bk = (const float*)d_in[2];
  const float* wv = (const float*)d_in[3];
  const float* bv = (const float*)d_in[4];
  const float* sk = (const float*)d_in[5];
  const float* sv = (const float*)d_in[6];
  const float* W1 = (const float*)d_in[7];
  const float* b1 = (const float*)d_in[8];
  const float* W2 = (const float*)d_in[9];
  const float* b2 = (const float*)d_in[10];
  float* out = (float*)d_out;
  float* ws  = (float*)d_ws;

  // workspace layout (floats)
  float* nk    = ws;                       // 1,605,632
  float* nv    = nk + 1605632;             // 1,605,632
  float* W2ws  = nv + 1605632;             // 1,605,632
  float* Spart = W2ws + 1605632;           // 1,605,632 (8x[64,3136] or 49x[64,512])
  float* Hb_sl = Spart + 1605632;          // 12,845,056 (49 x 262144)
  float* KKsl  = Hb_sl + 12845056;         // 7,225,344 (36 x 49 x 4096)
  float* Hbase = KKsl + 7225344;           // 262,144
  float* KKf   = Hbase + 262144;           // 147,456
  float* Hh    = KKf + 147456;             // 32,768
  float* G     = Hh + 32768;               // 32,768
  float* Gp    = G + 32768;                // 32,768
  float* Dw    = Gp + 32768;               // 200,704
  float* Ewst  = Dw + 200704;              // 262,144 (8 x 32768)
  float* Hcorr = Ewst + 262144;            // 229,376 (7 x 32768)
  float* b1ws  = Hcorr + 229376;           // 512
  float* b2ws  = b1ws + 512;               // 3,136

  // weights[i] = ETA0 * ALPHA^i * (ALPHA^63 / ALPHA^i) = ETA0 * ALPHA^63 (constant)
  float wc2 = 2.0f * (float)(0.1 * pow(0.9, 63.0));

  conv_rms<<<1568, 256, 0, stream>>>(x, wk, bk, wv, bv, sk, sv, nk, nv);
  u1_kernel<<<4900, 256, 0, stream>>>(nk, W1, KKsl, Hb_sl);
  u2_kernel<<<1600, 256, 0, stream>>>(KKsl, Hb_sl, KKf, Hbase);

  for (int ch = 0; ch < 8; ++ch) {
    const float* V   = nv + (size_t)ch * 200704;
    const float* b1c = ch ? b1ws : b1;
    const float* b2c = ch ? b2ws : b2;
    const float* W2c = ch ? W2ws : W2;
    float* Ewc = Ewst + (size_t)ch * 32768;
    int tri = ch * (ch + 1) / 2;

    if (ch == 0)
      hred_gelu<<<128, 256, 0, stream>>>(Hbase, Hcorr, 0, b1c, Hh, G, Gp);
    // P3: pred slices = G @ W2c (split-K 8)
    mm64_nn<<<dim3(49, 8), 256, 0, stream>>>(G, DH, W2c, DM, Spart, DM);
    // Dw = wc2*(pred + b2 - V); b2ws = b2c - colsum(Dw)
    red_Db2<<<49, 256, 0, stream>>>(Spart, b2c, V, wc2, Dw, b2ws);
    // P4: E slices = Dw @ W2c^T (split-K 49)
    mm64_nt<<<dim3(8, 49), 256, 0, stream>>>(Dw, DM, W2c, DM, Spart, DH);
    // P5: W2ws = W2c - G^T Dw  ||  Ew_c = redE*Gp, b1ws = b1c - colsum(Ew)
    comb5<<<520, 256, 0, stream>>>(G, Dw, W2c, W2ws, Spart, Gp, Ewc, b1c, b1ws);
    // G2 = gelu(H - KK[c,c]@Ew_c + b1ws)  ||  Hcorr slices for chunk ch+1
    g2h_kernel<<<96, 256, 0, stream>>>(KKf, tri, ch, Ewst, Hh, b1ws, G, Hcorr);
    // P7: Y slices = G2 @ W2ws (split-K 8)
    mm64_nn<<<dim3(49, 8), 256, 0, stream>>>(G, DH, W2ws, DM, Spart, DM);
    // out rows = sum + b2ws  ||  H/G/Gp for chunk ch+1
    redy_hg<<<912, 256, 0, stream>>>(Spart, b2ws, out, ch * 64,
                                     ch < 7 ? 1 : 0,
                                     Hbase + (size_t)(ch + 1) * 32768, Hcorr,
                                     ch + 1, b1ws, Hh, G, Gp);
  }
}